// Round 1
// baseline (5738.997 us; speedup 1.0000x reference)
//
#include <hip/hip_runtime.h>
#include <math.h>

// MDN-RNN: B=128, T=512, Z=32, A=3, H=256, K=5, IN=35, 4H=1024, MDN=325
#define T_LEN 512
#define B_SZ  128
#define H_DIM 256
#define G_DIM 1024
#define IN_D  35
#define MDN_D 325
#define K_MIX 5

// d_out layout: log_pi[B,T,5] | mu[B,T,5,32] | sigma[B,T,5,32] | c[B,256] | h[B,256]
static constexpr long OFF_MU    = 327680L;
static constexpr long OFF_SIGMA = 10813440L;
static constexpr long OFF_C     = 21299200L;
static constexpr long OFF_H     = 21331968L;

__device__ __forceinline__ float sigmf(float x) { return 1.0f / (1.0f + __expf(-x)); }

// One block = 2 batch elements (amortize Wh L2 reads), 1024 threads = one gate column each.
// 64 blocks; per step: gates = b + x@Wx + h@Wh, then 512 combine threads update c,h.
__global__ __launch_bounds__(1024, 1) void lstm_kernel(
    const float* __restrict__ z_t, const float* __restrict__ a_t,
    const float* __restrict__ Wx,  const float* __restrict__ Wh,
    const float* __restrict__ bias, float* __restrict__ outputs,
    float* __restrict__ out_c, float* __restrict__ out_h)
{
    __shared__ __align__(16) float x0[36];
    __shared__ __align__(16) float x1[36];
    __shared__ __align__(16) float h0[H_DIM];
    __shared__ __align__(16) float h1[H_DIM];
    __shared__ __align__(16) float g0[G_DIM];
    __shared__ __align__(16) float g1[G_DIM];

    const int tid = threadIdx.x;
    const int b0 = blockIdx.x * 2;
    const int b1 = b0 + 1;

    if (tid < H_DIM) { h0[tid] = 0.0f; h1[tid] = 0.0f; }
    const float bg = bias[tid];
    float c0 = 0.0f, c1 = 0.0f;   // live in combine threads only

    const float* z0p = z_t + (size_t)b0 * T_LEN * 32;
    const float* z1p = z_t + (size_t)b1 * T_LEN * 32;
    const float* a0p = a_t + (size_t)b0 * T_LEN * 3;
    const float* a1p = a_t + (size_t)b1 * T_LEN * 3;

    __syncthreads();

    for (int t = 0; t < T_LEN; ++t) {
        // stage x = concat(z,a) for both batches (waves 0 and 1)
        if (tid < IN_D)
            x0[tid] = (tid < 32) ? z0p[t*32 + tid] : a0p[t*3 + (tid - 32)];
        if (tid >= 64 && tid < 64 + IN_D) {
            int i = tid - 64;
            x1[i] = (i < 32) ? z1p[t*32 + i] : a1p[t*3 + (i - 32)];
        }
        __syncthreads();

        float acc0 = bg, acc1 = bg;

        // x @ Wx  (Wx streamed from L2, 143 KB resident)
        {
            const float* wxp = Wx + tid;
            #pragma unroll
            for (int i = 0; i < IN_D; ++i) {
                float w = *wxp; wxp += G_DIM;
                acc0 = fmaf(x0[i], w, acc0);
                acc1 = fmaf(x1[i], w, acc1);
            }
        }
        // h @ Wh  (h broadcast from LDS as float4, Wh from L2, shared across both batches)
        {
            const float* wp = Wh + tid;
            const float4* h04 = (const float4*)h0;
            const float4* h14 = (const float4*)h1;
            #pragma unroll 8
            for (int k4 = 0; k4 < H_DIM/4; ++k4) {
                float4 ha = h04[k4];
                float4 hb = h14[k4];
                float w0 = wp[0*G_DIM];
                float w1 = wp[1*G_DIM];
                float w2 = wp[2*G_DIM];
                float w3 = wp[3*G_DIM];
                wp += 4*G_DIM;
                acc0 = fmaf(ha.x, w0, acc0); acc0 = fmaf(ha.y, w1, acc0);
                acc0 = fmaf(ha.z, w2, acc0); acc0 = fmaf(ha.w, w3, acc0);
                acc1 = fmaf(hb.x, w0, acc1); acc1 = fmaf(hb.y, w1, acc1);
                acc1 = fmaf(hb.z, w2, acc1); acc1 = fmaf(hb.w, w3, acc1);
            }
        }
        g0[tid] = acc0;
        g1[tid] = acc1;
        __syncthreads();

        // combine: waves 0-3 -> batch0, waves 4-7 -> batch1 (wave-uniform branches)
        if (tid < 2*H_DIM) {
            const int  j     = tid & (H_DIM - 1);
            const bool first = (tid < H_DIM);
            const float* gb  = first ? g0 : g1;
            float cc         = first ? c0 : c1;
            float gi = gb[0*H_DIM + j];
            float gf = gb[1*H_DIM + j];
            float gg = gb[2*H_DIM + j];
            float go = gb[3*H_DIM + j];
            float iv = sigmf(gi), fv = sigmf(gf), ov = sigmf(go);
            float gv = tanhf(gg);
            cc = fmaf(fv, cc, iv * gv);
            float hv = ov * tanhf(cc);
            if (first) { c0 = cc; h0[j] = hv; }
            else       { c1 = cc; h1[j] = hv; }
            const int bb = first ? b0 : b1;
            outputs[((size_t)bb * T_LEN + t) * H_DIM + j] = hv;
            if (t == T_LEN - 1) {
                out_c[bb * H_DIM + j] = cc;
                out_h[bb * H_DIM + j] = hv;
            }
        }
        __syncthreads();
    }
}

// mdn = outputs @ Wd + bd, fused log_softmax(log_pi) and exp(log_sigma)+1e-6.
// 16 rows per block (Wd re-read /16), 256 threads, 2 columns per thread.
__global__ __launch_bounds__(256, 1) void mdn_kernel(
    const float* __restrict__ outputs, const float* __restrict__ Wd,
    const float* __restrict__ bd, float* __restrict__ out)
{
    __shared__ __align__(16) float hT[H_DIM * 16];   // hT[k*16 + r], 16 KB
    __shared__ float lp[16][K_MIX];

    const int tid = threadIdx.x;
    const long row0 = (long)blockIdx.x * 16;

    // load 16 rows of h, transposed (coalesced global reads)
    for (int idx = tid; idx < H_DIM * 16; idx += 256) {
        int r = idx >> 8;
        int k = idx & (H_DIM - 1);
        hT[k*16 + r] = outputs[(row0 + r) * H_DIM + k];
    }
    __syncthreads();

    const int  cA = tid;
    const int  cB = tid + 256;
    const bool vB = (cB < MDN_D);
    const float bA = bd[cA];
    const float bB = vB ? bd[cB] : 0.0f;
    float accA[16], accB[16];
    #pragma unroll
    for (int r = 0; r < 16; ++r) { accA[r] = bA; accB[r] = bB; }

    for (int k = 0; k < H_DIM; ++k) {
        float wA = Wd[(size_t)k * MDN_D + cA];
        float wB = vB ? Wd[(size_t)k * MDN_D + cB] : 0.0f;
        const float4* hp = (const float4*)(hT + k*16);
        float4 h0 = hp[0], h1 = hp[1], h2 = hp[2], h3 = hp[3];
        float hr[16] = { h0.x,h0.y,h0.z,h0.w, h1.x,h1.y,h1.z,h1.w,
                         h2.x,h2.y,h2.z,h2.w, h3.x,h3.y,h3.z,h3.w };
        #pragma unroll
        for (int r = 0; r < 16; ++r) {
            accA[r] = fmaf(hr[r], wA, accA[r]);
            accB[r] = fmaf(hr[r], wB, accB[r]);
        }
    }

    float* out_mu = out + OFF_MU;
    float* out_sg = out + OFF_SIGMA;
    #pragma unroll
    for (int r = 0; r < 16; ++r) {
        long row = row0 + r;
        float v = accA[r];
        if (cA < K_MIX)            lp[r][cA] = v;
        else if (cA < K_MIX + 160) out_mu[row*160 + (cA - K_MIX)] = v;
        else                       out_sg[row*160 + (cA - 165)]   = __expf(v) + 1e-6f;
        if (vB)                    out_sg[row*160 + (cB - 165)]   = __expf(accB[r]) + 1e-6f;
    }
    __syncthreads();

    // log_softmax over the 5 mixture logits, one thread per row
    if (tid < 16) {
        int r = tid;
        long row = row0 + r;
        float v0 = lp[r][0], v1 = lp[r][1], v2 = lp[r][2], v3 = lp[r][3], v4 = lp[r][4];
        float m = fmaxf(fmaxf(fmaxf(v0, v1), fmaxf(v2, v3)), v4);
        float s = __expf(v0-m) + __expf(v1-m) + __expf(v2-m) + __expf(v3-m) + __expf(v4-m);
        float ls = m + __logf(s);
        out[row*5 + 0] = v0 - ls;
        out[row*5 + 1] = v1 - ls;
        out[row*5 + 2] = v2 - ls;
        out[row*5 + 3] = v3 - ls;
        out[row*5 + 4] = v4 - ls;
    }
}

extern "C" void kernel_launch(void* const* d_in, const int* in_sizes, int n_in,
                              void* d_out, int out_size, void* d_ws, size_t ws_size,
                              hipStream_t stream)
{
    const float* z_t = (const float*)d_in[0];
    const float* a_t = (const float*)d_in[1];
    const float* Wx  = (const float*)d_in[2];
    const float* Wh  = (const float*)d_in[3];
    const float* b   = (const float*)d_in[4];
    const float* Wd  = (const float*)d_in[5];
    const float* bd  = (const float*)d_in[6];
    float* out = (float*)d_out;
    float* outputs = (float*)d_ws;   // needs B*T*H*4 = 64 MiB of scratch

    lstm_kernel<<<B_SZ/2, 1024, 0, stream>>>(z_t, a_t, Wx, Wh, b, outputs,
                                             out + OFF_C, out + OFF_H);
    mdn_kernel<<<(B_SZ*T_LEN)/16, 256, 0, stream>>>(outputs, Wd, bd, out);
}